// Round 2
// 466.034 us; speedup vs baseline: 1.1018x; 1.1018x over previous
//
#include <hip/hip_runtime.h>
#include <math.h>

#define D_MODEL 1024
#define SEQ 2048
#define BATCH 8
#define ROWS (BATCH*SEQ)   // 16384

typedef __attribute__((ext_vector_type(8))) short bf16x8;  // 8 bf16 (4 VGPRs)
typedef __attribute__((ext_vector_type(4))) float f32x4;

__device__ __forceinline__ unsigned short f2bf(float f) {
  union { float f; unsigned u; } x; x.f = f;
  unsigned r = x.u + 0x7fffu + ((x.u >> 16) & 1u);   // RNE
  return (unsigned short)(r >> 16);
}

// async 16B global -> LDS (DMA; LDS dest is wave-uniform base + lane*16,
// which our tid*16B layout satisfies exactly)
__device__ __forceinline__ void gld16(const unsigned short* g, unsigned short* l) {
  __builtin_amdgcn_global_load_lds(
      (const __attribute__((address_space(1))) unsigned int*)g,
      (__attribute__((address_space(3))) unsigned int*)l, 16, 0, 0);
}

#define BAR() __builtin_amdgcn_s_barrier()

// ---------------------------------------------------------------------------
// 256x256 tile, BK=64, 8 waves (2M x 4N), 4 phases / K-tile, counted vmcnt.
// LDS: S[buf][mat A/B][khalf][256*32 shorts] = 128 KiB. Zero-conflict chunk
// swizzle carried over from the 128^2 kernel: slot s=(quad+(R>>1))&3, global
// chunk u=((tid&3)-(sr>>1))&3 (pass1 row +128 == same u mod 4).
//
// Schedule per tile v (p=v&1), hazard-audited:
//  ph0: vmcnt(4|0); BAR; read A(ks0,mi0-3)+B(ks0); stage (v+1).khiA->buf[p^1];
//       BAR; 16 MFMA
//  ph1: BAR; read A(ks0,mi4-7); stage (v+1).khiB->buf[p^1]; BAR; 16 MFMA
//  ph2: BAR; read A(ks1,mi0-3)+B(ks1); stage (v+2).kloA->buf[p]; BAR; 16 MFMA
//  ph3: BAR; read A(ks1,mi4-7); stage (v+2).kloB->buf[p]; BAR; 16 MFMA
// Boundary vmcnt(4): exactly the 4 loads of (v+2).klo are younger than tile
// (v+1)'s last half-tile, so per-wave vmcnt(4) BEFORE the barrier proves all
// of tile (v+1) landed for that wave; barrier-exit extends this to all waves.
// Last tile has no younger loads -> vmcnt(0) there. Stage targets provably
// dead: khi of buf[p^1] last read at (v-1).ph3 (reads lgkm-drained before
// that phase's MFMA, which precedes this tile's leading BAR); klo of buf[p]
// last read at v.ph1. Loads never drain to 0 mid-loop (T4); setprio brackets
// each MFMA cluster (T5).
// EPI: 0 = bf16 store; 1 = exp + l/t row-sum atomics; 2 = *1/l + bias, fp32.
// ---------------------------------------------------------------------------
template<int EPI>
__global__ __launch_bounds__(512, 2)
void gemm_b(const unsigned short* __restrict__ A, const unsigned short* __restrict__ B,
            void* __restrict__ Cp, int lda, int ldb, int ldc, int K,
            size_t sA, size_t sB, size_t sC, float scale,
            float* __restrict__ lsum, float* __restrict__ tsum, int lstride,
            const float* __restrict__ bias)
{
  __shared__ __align__(16) unsigned short S[2][2][2][8192];   // 128 KiB
  const int tid  = threadIdx.x;
  const int lane = tid & 63;
  const int wid  = tid >> 6;                 // 0..7
  const int quad = lane >> 4, l16 = lane & 15;
  const int wr = wid >> 2, wc = wid & 3;     // 2 x 4 wave grid
  const int m0 = blockIdx.y * 256, n0 = blockIdx.x * 256;
  const int bz = blockIdx.z;

  // staging coords: thread covers rows sr and sr+128 at swizzled 16B chunk u
  const int sr = tid >> 2;                       // 0..127
  const int u  = ((tid & 3) - (sr >> 1)) & 3;    // global chunk (both passes)
  const unsigned short* Ag0 = A + (size_t)bz * sA + (size_t)(m0 + sr) * lda + u * 8;
  const unsigned short* Ag1 = Ag0 + (size_t)128 * lda;
  const unsigned short* Bg0 = B + (size_t)bz * sB + (size_t)(n0 + sr) * ldb + u * 8;
  const unsigned short* Bg1 = Bg0 + (size_t)128 * ldb;
  const int ldst = tid * 8;                      // lds short offset, pass 0

  f32x4 acc[8][4];
#pragma unroll
  for (int i = 0; i < 8; i++)
#pragma unroll
    for (int j = 0; j < 4; j++) acc[i][j] = (f32x4){0.f, 0.f, 0.f, 0.f};

  const int NT = K >> 6;

#define STG(mat, bufp, ks, koff) do { \
    gld16(((mat) ? Bg0 : Ag0) + (koff), &S[bufp][mat][ks][ldst]); \
    gld16(((mat) ? Bg1 : Ag1) + (koff), &S[bufp][mat][ks][4096 + ldst]); \
  } while (0)

#define LOAD_A(mih, ks, p) do { \
    _Pragma("unroll") \
    for (int i = 0; i < 4; i++) { \
      const int R = wr * 128 + ((mih) * 4 + i) * 16 + l16; \
      const int s = (quad + (R >> 1)) & 3; \
      af[i] = *(const bf16x8*)&S[p][0][ks][R * 32 + s * 8]; \
    } } while (0)

#define LOAD_B(ks, p) do { \
    _Pragma("unroll") \
    for (int j = 0; j < 4; j++) { \
      const int R = wc * 64 + j * 16 + l16; \
      const int s = (quad + (R >> 1)) & 3; \
      bfr[j] = *(const bf16x8*)&S[p][1][ks][R * 32 + s * 8]; \
    } } while (0)

#define MFMA16(mih) do { \
    _Pragma("unroll") \
    for (int i = 0; i < 4; i++) \
    _Pragma("unroll") \
    for (int j = 0; j < 4; j++) \
      acc[(mih) * 4 + i][j] = __builtin_amdgcn_mfma_f32_16x16x32_bf16( \
          af[i], bfr[j], acc[(mih) * 4 + i][j], 0, 0, 0); \
  } while (0)

  // prologue: tile0 complete + tile1 k-lo (6 half-tiles, 12 loads in flight)
  STG(0, 0, 0, 0);  STG(1, 0, 0, 0);     // t0.kloA, t0.kloB
  STG(0, 0, 1, 32); STG(1, 0, 1, 32);    // t0.khiA, t0.khiB
  if (NT > 1) { STG(0, 1, 0, 64); STG(1, 1, 0, 64); }   // t1.kloA/B

  for (int v = 0; v < NT; ++v) {
    const int p = v & 1;
    const int kHi = (v + 1) * 64 + 32;
    const int kLo = (v + 2) * 64;
    bf16x8 af[4], bfr[4];
    // ---- ph0 (boundary) ----
    if (v + 1 < NT) asm volatile("s_waitcnt vmcnt(4)" ::: "memory");
    else            asm volatile("s_waitcnt vmcnt(0)" ::: "memory");
    BAR();
    LOAD_A(0, 0, p); LOAD_B(0, p);
    if (v + 1 < NT) STG(0, p ^ 1, 1, kHi);
    BAR();
    __builtin_amdgcn_s_setprio(1); MFMA16(0); __builtin_amdgcn_s_setprio(0);
    // ---- ph1 ----
    BAR();
    LOAD_A(1, 0, p);
    if (v + 1 < NT) STG(1, p ^ 1, 1, kHi);
    BAR();
    __builtin_amdgcn_s_setprio(1); MFMA16(1); __builtin_amdgcn_s_setprio(0);
    // ---- ph2 ----
    BAR();
    LOAD_A(0, 1, p); LOAD_B(1, p);
    if (v + 2 < NT) STG(0, p, 0, kLo);
    BAR();
    __builtin_amdgcn_s_setprio(1); MFMA16(0); __builtin_amdgcn_s_setprio(0);
    // ---- ph3 ----
    BAR();
    LOAD_A(1, 1, p);
    if (v + 2 < NT) STG(1, p, 0, kLo);
    BAR();
    __builtin_amdgcn_s_setprio(1); MFMA16(1); __builtin_amdgcn_s_setprio(0);
  }

#undef STG
#undef LOAD_A
#undef LOAD_B
#undef MFMA16

  // epilogue — C/D layout: col = lane&15, row = quad*4 + reg  [m89-verified]
  if constexpr (EPI == 0) {
    unsigned short* C = (unsigned short*)Cp + (size_t)bz * sC;
#pragma unroll
    for (int mi = 0; mi < 8; mi++)
#pragma unroll
      for (int r = 0; r < 4; r++) {
        const int grow = m0 + wr * 128 + mi * 16 + quad * 4 + r;
#pragma unroll
        for (int ni = 0; ni < 4; ni++) {
          const int gcol = n0 + wc * 64 + ni * 16 + l16;
          C[(size_t)grow * ldc + gcol] = f2bf(acc[mi][ni][r]);
        }
      }
  } else if constexpr (EPI == 1) {
    unsigned short* C = (unsigned short*)Cp + (size_t)bz * sC;
#pragma unroll
    for (int mi = 0; mi < 8; mi++)
#pragma unroll
      for (int r = 0; r < 4; r++) {
        const int grow = m0 + wr * 128 + mi * 16 + quad * 4 + r;
        float es = 0.f, ts = 0.f;
#pragma unroll
        for (int ni = 0; ni < 4; ni++) {
          const int gcol = n0 + wc * 64 + ni * 16 + l16;
          float s = acc[mi][ni][r] * scale;
          float e = __expf(s);
          es += e; ts += s * e;
          C[(size_t)grow * ldc + gcol] = f2bf(e);
        }
#pragma unroll
        for (int off = 1; off < 16; off <<= 1) {
          es += __shfl_xor(es, off, 64);
          ts += __shfl_xor(ts, off, 64);
        }
        if (l16 == 0) {
          atomicAdd(&lsum[bz * lstride + grow], es);
          atomicAdd(&tsum[bz * lstride + grow], ts);
        }
      }
  } else {
    float* C = (float*)Cp + (size_t)bz * sC;
#pragma unroll
    for (int mi = 0; mi < 8; mi++)
#pragma unroll
      for (int r = 0; r < 4; r++) {
        const int grow = m0 + wr * 128 + mi * 16 + quad * 4 + r;
        const float linv = 1.0f / lsum[bz * lstride + grow];
#pragma unroll
        for (int ni = 0; ni < 4; ni++) {
          const int gcol = n0 + wc * 64 + ni * 16 + l16;
          C[(size_t)grow * ldc + gcol] = acc[mi][ni][r] * linv + bias[gcol];
        }
      }
  }
}

// fp32 -> bf16, 8 elems/thread
__global__ __launch_bounds__(256)
void cvt_k(const float* __restrict__ src, unsigned short* __restrict__ dst, int n8)
{
  int stride = gridDim.x * 256;
  for (int i = blockIdx.x * 256 + threadIdx.x; i < n8; i += stride) {
    const float4* s = (const float4*)(src + (size_t)i * 8);
    float4 a = s[0], b = s[1];
    union { unsigned short v[8]; uint4 u; } o;
    o.v[0] = f2bf(a.x); o.v[1] = f2bf(a.y); o.v[2] = f2bf(a.z); o.v[3] = f2bf(a.w);
    o.v[4] = f2bf(b.x); o.v[5] = f2bf(b.y); o.v[6] = f2bf(b.z); o.v[7] = f2bf(b.w);
    *(uint4*)(dst + (size_t)i * 8) = o.u;
  }
}

// W [1024x1024] fp32 -> WT bf16 (WT[e][d] = W[d][e])
__global__ __launch_bounds__(256)
void wtr_k(const float* __restrict__ W, unsigned short* __restrict__ WT)
{
  __shared__ float t[32][33];
  int bx = blockIdx.x * 32, by = blockIdx.y * 32;
  int tx = threadIdx.x & 31, ty = threadIdx.x >> 5;   // ty 0..7
#pragma unroll
  for (int i = 0; i < 32; i += 8)
    t[ty + i][tx] = W[(size_t)(by + ty + i) * D_MODEL + bx + tx];
  __syncthreads();
#pragma unroll
  for (int i = 0; i < 32; i += 8)
    WT[(size_t)(bx + ty + i) * D_MODEL + by + tx] = f2bf(t[tx][ty + i]);
}

// In-place layernorm over rows of 1024 floats (float4 vectorized).
__global__ __launch_bounds__(256)
void ln_k(float* __restrict__ out, const float* __restrict__ gamma,
          const float* __restrict__ beta)
{
  const size_t row = blockIdx.x;
  float4* p = (float4*)(out + row * D_MODEL);
  const int tid = threadIdx.x;
  float4 v = p[tid];
  float s  = v.x + v.y + v.z + v.w;
  float sq = v.x * v.x + v.y * v.y + v.z * v.z + v.w * v.w;
#pragma unroll
  for (int off = 1; off < 64; off <<= 1) {
    s  += __shfl_xor(s, off, 64);
    sq += __shfl_xor(sq, off, 64);
  }
  __shared__ float sh[8];
  int wv = tid >> 6, lane = tid & 63;
  if (lane == 0) { sh[wv] = s; sh[4 + wv] = sq; }
  __syncthreads();
  s  = sh[0] + sh[1] + sh[2] + sh[3];
  sq = sh[4] + sh[5] + sh[6] + sh[7];
  float mean = s * (1.f / 1024.f);
  float var  = sq * (1.f / 1024.f) - mean * mean;
  float rstd = rsqrtf(var + 1e-5f);
  float4 g = ((const float4*)gamma)[tid];
  float4 b = ((const float4*)beta)[tid];
  v.x = (v.x - mean) * rstd * g.x + b.x;
  v.y = (v.y - mean) * rstd * g.y + b.y;
  v.z = (v.z - mean) * rstd * g.z + b.z;
  v.w = (v.w - mean) * rstd * g.w + b.w;
  p[tid] = v;
}

// syntony = clip(1 - mean(log l - t/l)/log(S), 0, 1)
__global__ __launch_bounds__(256)
void syn_k(const float* __restrict__ l, const float* __restrict__ t,
           float* __restrict__ out)
{
  float s = 0.f;
  for (int r = threadIdx.x; r < ROWS; r += 256) {
    float lv = l[r];
    s += logf(lv) - t[r] / lv;
  }
#pragma unroll
  for (int off = 1; off < 64; off <<= 1) s += __shfl_xor(s, off, 64);
  __shared__ float sh[4];
  if ((threadIdx.x & 63) == 0) sh[threadIdx.x >> 6] = s;
  __syncthreads();
  if (threadIdx.x == 0) {
    float tot  = sh[0] + sh[1] + sh[2] + sh[3];
    float ment = tot / (float)ROWS;
    float syn  = 1.0f - ment / logf((float)SEQ);
    syn = fminf(fmaxf(syn, 0.f), 1.f);
    out[(size_t)ROWS * D_MODEL] = syn;
  }
}

extern "C" void kernel_launch(void* const* d_in, const int* in_sizes, int n_in,
                              void* d_out, int out_size, void* d_ws, size_t ws_size,
                              hipStream_t stream)
{
  const float* q     = (const float*)d_in[0];
  const float* k     = (const float*)d_in[1];
  const float* v     = (const float*)d_in[2];
  const float* hw    = (const float*)d_in[3];
  const float* hb    = (const float*)d_in[4];
  const float* gamma = (const float*)d_in[5];
  const float* beta  = (const float*)d_in[6];
  float* out = (float*)d_out;

  // ---- workspace: EXACTLY the round-1-proven 96.13 MB footprint ----
  const size_t MB = 1024ull * 1024ull;
  char* ws = (char*)d_ws;
  unsigned short* P   = (unsigned short*)(ws);            // [ 0,64) MB  P bf16
  unsigned short* VWT = (unsigned short*)(ws + 64 * MB);  // [64,96) MB  VWT bf16
  float* lsum = (float*)(ws + 96 * MB);                   // 64 KB
  float* tsum = lsum + ROWS;                              // 64 KB

  // ---- d_out doubles as staging scratch until phase C overwrites it ----
  unsigned short* Vb = (unsigned short*)out;
  unsigned short* WT = (unsigned short*)((char*)out + 32 * MB);
  unsigned short* Qb = (unsigned short*)out;
  unsigned short* Kb = (unsigned short*)((char*)out + 32 * MB);

  hipMemsetAsync(lsum, 0, 2 * ROWS * sizeof(float), stream);

  const int n8 = ROWS * D_MODEL / 8;

  // phase A: VWT = WT . Vb^T   (M=1024, N=16384, K=1024)
  cvt_k<<<4096, 256, 0, stream>>>(v, Vb, n8);
  wtr_k<<<dim3(32, 32), 256, 0, stream>>>(hw, WT);
  gemm_b<0><<<dim3(ROWS / 256, D_MODEL / 256, 1), 512, 0, stream>>>(
      WT, Vb, VWT, D_MODEL, D_MODEL, ROWS, D_MODEL,
      0, 0, 0, 1.f, nullptr, nullptr, 0, nullptr);

  // phase B: P = exp(Qb Kb^T / 32) + row sums l,t   (Vb/WT dead -> reuse)
  cvt_k<<<4096, 256, 0, stream>>>(q, Qb, n8);
  cvt_k<<<4096, 256, 0, stream>>>(k, Kb, n8);
  gemm_b<1><<<dim3(SEQ / 256, SEQ / 256, BATCH), 512, 0, stream>>>(
      Qb, Kb, P, D_MODEL, D_MODEL, SEQ, D_MODEL,
      (size_t)SEQ * D_MODEL, (size_t)SEQ * D_MODEL, (size_t)SEQ * SEQ,
      0.03125f, lsum, tsum, SEQ, nullptr);

  // phase C: out = (P . VWT^T)/l + bias   (Qb/Kb dead; out overwritten)
  // per-batch B offset is a COLUMN offset into VWT: sB = 2048 elements.
  gemm_b<2><<<dim3(D_MODEL / 256, SEQ / 256, BATCH), 512, 0, stream>>>(
      P, VWT, out, SEQ, ROWS, D_MODEL, SEQ,
      (size_t)SEQ * SEQ, (size_t)SEQ, (size_t)SEQ * D_MODEL,
      1.f, lsum, tsum, SEQ, hb);

  ln_k<<<ROWS, 256, 0, stream>>>(out, gamma, beta);
  syn_k<<<1, 256, 0, stream>>>(lsum, tsum, out);
}